// Round 7
// baseline (43.415 us; speedup 1.0000x reference)
//
#include <hip/hip_runtime.h>
#include <math.h>

#define KK 20
#define NPTS 8192
#define NQB 8               // queries per block
#define QPL 4               // queries per lane
#define NCH 256             // chunks per query
#define THREADS 512
#define WIN 1024            // points per staged LDS window
#define NWIN 8
#define JPW (WIN / NCH)     // 4 candidates per chunk per window
#define PPT (WIN / THREADS) // 2 points staged per thread
#define CAP 64              // hit buffer capacity per query
#define MARGIN 4e-3f        // >> 2*max|d_fma - d_exact| for this input range

// Exact (non-contracted) IEEE ops matching the NumPy reference bit-for-bit.
// np.sum (pairwise, n<8) accumulates ascending: (x^2 + y^2) + z^2.
__device__ __forceinline__ float norm3(float x, float y, float z) {
    return __fadd_rn(__fadd_rn(__fmul_rn(x, x), __fmul_rn(y, y)), __fmul_rn(z, z));
}

// np.einsum (optimize=False) remainder falls through DESCENDING for count=3:
// ((z*z') + y*y') + x*x'.  dist = ((-2*dot) + n_src) + n_dst.
__device__ __forceinline__ float dist_exact(float px, float py, float pz, float pw,
                                            float qx, float qy, float qz, float qn) {
    const float dot = __fadd_rn(
        __fadd_rn(__fmul_rn(pz, qz), __fmul_rn(py, qy)), __fmul_rn(px, qx));
    return __fadd_rn(__fadd_rn(__fmul_rn(dot, -2.0f), pw), qn);
}

// Contracted fast distance for threshold/filter only (margin covers the diff).
__device__ __forceinline__ float dist_fast(float px, float py, float pz, float pw,
                                           float qx, float qy, float qz, float qn) {
    const float dot = __builtin_fmaf(pz, qz, __builtin_fmaf(py, qy, px * qx));
    return __builtin_fmaf(dot, -2.0f, pw) + qn;
}

extern "C" __global__ __launch_bounds__(THREADS, 8)
void knn_kernel(const float* __restrict__ verts, int* __restrict__ out)
{
    // Static LDS ~29.8 KB -> 4 blocks/CU (32 waves/CU).
    __shared__ float4 pts[WIN];                 // 16384 B
    __shared__ float  vdump[NCH][NQB + 1];      //  9216 B
    __shared__ float  hbd[NQB][CAP];            //  2048 B
    __shared__ int    hbi[NQB][CAP];            //  2048 B
    __shared__ float  Tq[NQB];
    __shared__ int    cnt[NQB];

    const int t    = threadIdx.x;
    const int lane = t & 63;
    const int wv   = t >> 6;          // wave 0..7
    const int c    = t >> 1;          // chunk 0..255
    const int qh   = t & 1;           // query group 0..1
    const int xr   = c & 3;           // read-order bank-spread XOR (JPW=4)
    const int qbase = blockIdx.x * NQB + qh * QPL;

    if (t < NQB) cnt[t] = 0;

    // Register tile: 4 queries per lane, exact reference op-order norms.
    float qx[QPL], qy[QPL], qz[QPL], qn[QPL];
#pragma unroll
    for (int i = 0; i < QPL; ++i) {
        qx[i] = verts[(qbase + i) * 3 + 0];
        qy[i] = verts[(qbase + i) * 3 + 1];
        qz[i] = verts[(qbase + i) * 3 + 2];
        qn[i] = norm3(qx[i], qy[i], qz[i]);
    }

    // Issue-early / commit-late staging (T14).
    float sx[PPT], sy[PPT], sz[PPT];
    auto issue = [&](int w) {
#pragma unroll
        for (int i = 0; i < PPT; ++i) {
            const int n = w * WIN + i * THREADS + t;
            sx[i] = verts[n * 3 + 0];
            sy[i] = verts[n * 3 + 1];
            sz[i] = verts[n * 3 + 2];
        }
    };
    auto commit = [&]() {
#pragma unroll
        for (int i = 0; i < PPT; ++i) {
            const int m = i * THREADS + t;
            pts[m] = make_float4(sx[i], sy[i], sz[i], norm3(sx[i], sy[i], sz[i]));
        }
    };

    // ---------------- PASS 1: per-(chunk,query) MIN fast-distance -----------
    float mn[QPL];
#pragma unroll
    for (int i = 0; i < QPL; ++i) mn[i] = INFINITY;

    issue(0); commit(); __syncthreads();
#pragma unroll 1
    for (int w = 0; w < NWIN; ++w) {
        if (w + 1 < NWIN) issue(w + 1);
#pragma unroll
        for (int v = 0; v < JPW; ++v) {
            const float4 p = pts[c * JPW + (v ^ xr)];
#pragma unroll
            for (int i = 0; i < QPL; ++i)
                mn[i] = fminf(mn[i], dist_fast(p.x, p.y, p.z, p.w,
                                               qx[i], qy[i], qz[i], qn[i]));
        }
        __syncthreads();
        if (w + 1 < NWIN) { commit(); __syncthreads(); }
        // window NWIN-1 stays resident for pass 2
    }

#pragma unroll
    for (int i = 0; i < QPL; ++i) vdump[c][qh * QPL + i] = mn[i];
    __syncthreads();

    // ------- T' = 20th smallest of 256 chunk-minima (wave wv: query wv) -----
    {
        const int qq = wv;
        float r0 = vdump[lane * 4 + 0][qq];
        float r1 = vdump[lane * 4 + 1][qq];
        float r2 = vdump[lane * 4 + 2][qq];
        float r3 = vdump[lane * 4 + 3][qq];
        // stage k=2: (r0,r1) asc, (r2,r3) desc
        { const float lo = fminf(r0, r1), hi = fmaxf(r0, r1); r0 = lo; r1 = hi; }
        { const float lo = fminf(r2, r3), hi = fmaxf(r2, r3); r2 = hi; r3 = lo; }
#pragma unroll
        for (int k = 4; k <= 256; k <<= 1) {
            const bool asc = (((lane << 2) & k) == 0);
#pragma unroll
            for (int j = k >> 1; j >= 4; j >>= 1) {
                const int lj = j >> 2;
                const bool lower = ((lane & lj) == 0);
                const bool keepmin = (lower == asc);
                const float o0 = __shfl_xor(r0, lj), o1 = __shfl_xor(r1, lj);
                const float o2 = __shfl_xor(r2, lj), o3 = __shfl_xor(r3, lj);
                r0 = keepmin ? fminf(r0, o0) : fmaxf(r0, o0);
                r1 = keepmin ? fminf(r1, o1) : fmaxf(r1, o1);
                r2 = keepmin ? fminf(r2, o2) : fmaxf(r2, o2);
                r3 = keepmin ? fminf(r3, o3) : fmaxf(r3, o3);
            }
            { // j = 2: (r0,r2), (r1,r3)
                const float lo0 = fminf(r0, r2), hi0 = fmaxf(r0, r2);
                const float lo1 = fminf(r1, r3), hi1 = fmaxf(r1, r3);
                r0 = asc ? lo0 : hi0; r2 = asc ? hi0 : lo0;
                r1 = asc ? lo1 : hi1; r3 = asc ? hi1 : lo1;
            }
            { // j = 1: (r0,r1), (r2,r3)
                const float lo0 = fminf(r0, r1), hi0 = fmaxf(r0, r1);
                const float lo1 = fminf(r2, r3), hi1 = fmaxf(r2, r3);
                r0 = asc ? lo0 : hi0; r1 = asc ? hi0 : lo0;
                r2 = asc ? lo1 : hi1; r3 = asc ? hi1 : lo1;
            }
        }
        const float T = __shfl(r3, 4);          // element 19 = lane 4, reg 3
        if (lane == 0) Tq[qq] = T + MARGIN;
    }
    __syncthreads();

    float Tl[QPL];
#pragma unroll
    for (int i = 0; i < QPL; ++i) Tl[i] = Tq[qh * QPL + i];

    // -------- PASS 2: fast-filter, exact recompute for hits only ------------
    // Window NWIN-1 resident -> scan order {7,0,1,...,6}, prefetched.
#pragma unroll 1
    for (int ww = 0; ww < NWIN; ++ww) {
        const int w = (ww == 0) ? (NWIN - 1) : (ww - 1);
        if (ww + 1 < NWIN) issue(ww);
#pragma unroll
        for (int v = 0; v < JPW; ++v) {
            const int mloc = c * JPW + (v ^ xr);
            const float4 p = pts[mloc];
            const int n = w * WIN + mloc;      // logical candidate id
#pragma unroll
            for (int i = 0; i < QPL; ++i) {
                const float dfa = dist_fast(p.x, p.y, p.z, p.w,
                                            qx[i], qy[i], qz[i], qn[i]);
                if (dfa <= Tl[i]) {            // ~22 hits/query total
                    const float dex = dist_exact(p.x, p.y, p.z, p.w,
                                                 qx[i], qy[i], qz[i], qn[i]);
                    const int q = qh * QPL + i;
                    const int slot = atomicAdd(&cnt[q], 1);
                    if (slot < CAP) { hbd[q][slot] = dex; hbi[q][slot] = n; }
                }
            }
        }
        __syncthreads();
        if (ww + 1 < NWIN) { commit(); __syncthreads(); }
    }

    // ------- Final: exact stable top-20 via u64 bitonic (wave wv: query wv) --
    {
        const int qq = wv;
        const int kc = min(cnt[qq], CAP);      // kc >= 20 guaranteed
        unsigned long long key = ~0ULL;
        if (lane < kc) {
            const float d = hbd[qq][lane];
            unsigned u = __float_as_uint(d);
            u ^= ((unsigned)((int)u >> 31)) | 0x80000000u;   // order-preserving map
            key = ((unsigned long long)u << 32) | (unsigned)hbi[qq][lane];
        }
#pragma unroll
        for (int k = 2; k <= 64; k <<= 1) {
#pragma unroll
            for (int j = k >> 1; j >= 1; j >>= 1) {
                const unsigned long long o = __shfl_xor(key, j);
                const bool asc = ((lane & k) == 0);
                const bool lower = ((lane & j) == 0);
                const bool keepmin = (lower == asc);
                const bool lt = key < o;
                key = (keepmin == lt) ? key : o;
            }
        }
        if (lane < KK)
            out[(blockIdx.x * NQB + qq) * KK + lane] =
                (int)(unsigned)(key & 0xffffffffULL);
    }
}

extern "C" void kernel_launch(void* const* d_in, const int* in_sizes, int n_in,
                              void* d_out, int out_size, void* d_ws, size_t ws_size,
                              hipStream_t stream) {
    // d_in[0] = feats (unused). d_in[1] = vertices [4,8192,3] f32; batch 0 only.
    const float* verts = (const float*)d_in[1];
    int* out = (int*)d_out;
    knn_kernel<<<dim3(NPTS / NQB), dim3(THREADS), 0, stream>>>(verts, out);
}

// Round 9
// 35.679 us; speedup vs baseline: 1.2168x; 1.2168x over previous
//
#include <hip/hip_runtime.h>
#include <math.h>

#define KK 20
#define NPTS 8192
#define NQB 16              // queries per block
#define QPL 4               // queries per lane
#define NCH 128             // chunks per query (64 pts each, strided across windows)
#define THREADS 512
#define WIN 2048            // points per staged LDS window
#define NWIN 4
#define JPW (WIN / NCH)     // 16 candidates per chunk per window
#define PPT (WIN / THREADS) // 4 points staged per thread
#define CAP 64              // hit buffer capacity per query
#define MAXC 64             // candidate-chunk list capacity per query
#define MARGIN 4e-3f        // >> 2*max|d_fast - d_exact| (fp32 fma vs split)

// Exact (non-contracted) IEEE ops matching the NumPy reference bit-for-bit.
// np.sum (pairwise, n<8) accumulates ascending: (x^2 + y^2) + z^2.
__device__ __forceinline__ float norm3(float x, float y, float z) {
    return __fadd_rn(__fadd_rn(__fmul_rn(x, x), __fmul_rn(y, y)), __fmul_rn(z, z));
}

// np.einsum (optimize=False) remainder falls through DESCENDING for count=3:
// ((z*z') + y*y') + x*x'.  dist = ((-2*dot) + n_src) + n_dst.
__device__ __forceinline__ float dist_exact(float px, float py, float pz, float pw,
                                            float qx, float qy, float qz, float qn) {
    const float dot = __fadd_rn(
        __fadd_rn(__fmul_rn(pz, qz), __fmul_rn(py, qy)), __fmul_rn(px, qx));
    return __fadd_rn(__fadd_rn(__fmul_rn(dot, -2.0f), pw), qn);
}

// Contracted fast distance for chunk-minima / threshold only.
__device__ __forceinline__ float dist_fast(float px, float py, float pz, float pw,
                                           float qx, float qy, float qz, float qn) {
    const float dot = __builtin_fmaf(pz, qz, __builtin_fmaf(py, qy, px * qx));
    return __builtin_fmaf(dot, -2.0f, pw) + qn;
}

extern "C" __global__ __launch_bounds__(THREADS, 4)
void knn_kernel(const float* __restrict__ verts, int* __restrict__ out)
{
    // Static LDS ~58 KB -> 2 blocks/CU, grid 512 = exactly 2/CU.
    __shared__ float4 pts[WIN];                 // 32768 B
    __shared__ float  vdump[NCH][NQB + 1];      //  8704 B
    __shared__ float  hbd[NQB][CAP];            //  4096 B
    __shared__ int    hbi[NQB][CAP];            //  4096 B
    __shared__ int    cand[NQB][MAXC];          //  4096 B
    __shared__ float  Tq[NQB];
    __shared__ int    cnt[NQB];
    __shared__ int    cnt2[NQB];

    const int t    = threadIdx.x;
    const int lane = t & 63;
    const int wv   = t >> 6;          // wave 0..7
    const int c    = t >> 2;          // chunk 0..127
    const int qh   = t & 3;           // query group 0..3
    const int xr   = c & 15;          // read-order bank-spread XOR (R6-proven)
    const int qbase = blockIdx.x * NQB + qh * QPL;

    if (t < NQB) { cnt[t] = 0; cnt2[t] = 0; }

    // Register tile: 4 queries per lane, exact reference op-order norms.
    float qx[QPL], qy[QPL], qz[QPL], qn[QPL];
#pragma unroll
    for (int i = 0; i < QPL; ++i) {
        qx[i] = verts[(qbase + i) * 3 + 0];
        qy[i] = verts[(qbase + i) * 3 + 1];
        qz[i] = verts[(qbase + i) * 3 + 2];
        qn[i] = norm3(qx[i], qy[i], qz[i]);
    }

    // Issue-early / commit-late staging (T14).
    float sx[PPT], sy[PPT], sz[PPT];
    auto issue = [&](int w) {
#pragma unroll
        for (int i = 0; i < PPT; ++i) {
            const int n = w * WIN + i * THREADS + t;
            sx[i] = verts[n * 3 + 0];
            sy[i] = verts[n * 3 + 1];
            sz[i] = verts[n * 3 + 2];
        }
    };
    auto commit = [&]() {
#pragma unroll
        for (int i = 0; i < PPT; ++i) {
            const int m = i * THREADS + t;
            pts[m] = make_float4(sx[i], sy[i], sz[i], norm3(sx[i], sy[i], sz[i]));
        }
    };

    // ---------------- PASS 1: per-(chunk,query) MIN fast-distance -----------
    // Chunk c's point set: { w*WIN + c*JPW + j : w in [0,NWIN), j in [0,JPW) }.
    float mn[QPL];
#pragma unroll
    for (int i = 0; i < QPL; ++i) mn[i] = INFINITY;

    issue(0); commit(); __syncthreads();
#pragma unroll 1
    for (int w = 0; w < NWIN; ++w) {
        if (w + 1 < NWIN) issue(w + 1);
#pragma unroll 4
        for (int v = 0; v < JPW; ++v) {
            const float4 p = pts[c * JPW + (v ^ xr)];
#pragma unroll
            for (int i = 0; i < QPL; ++i)
                mn[i] = fminf(mn[i], dist_fast(p.x, p.y, p.z, p.w,
                                               qx[i], qy[i], qz[i], qn[i]));
        }
        __syncthreads();
        if (w + 1 < NWIN) { commit(); __syncthreads(); }
    }

#pragma unroll
    for (int i = 0; i < QPL; ++i) vdump[c][qh * QPL + i] = mn[i];
    __syncthreads();

    // ------- T' = 20th smallest of 128 chunk-minima + margin ----------------
    // Wave wv handles queries {2wv, 2wv+1}: 128-elem bitonic, 2 regs/lane.
#pragma unroll
    for (int r = 0; r < 2; ++r) {
        const int qq = wv * 2 + r;
        float v0 = vdump[lane * 2 + 0][qq];
        float v1 = vdump[lane * 2 + 1][qq];
#pragma unroll
        for (int k = 2; k <= 128; k <<= 1) {
#pragma unroll
            for (int j = k >> 1; j >= 1; j >>= 1) {
                const bool asc = ((lane & (k >> 1)) == 0);
                if (j == 1) {
                    const float lo = fminf(v0, v1), hi = fmaxf(v0, v1);
                    v0 = asc ? lo : hi;
                    v1 = asc ? hi : lo;
                } else {
                    const int jj = j >> 1;
                    const float o0 = __shfl_xor(v0, jj);
                    const float o1 = __shfl_xor(v1, jj);
                    const bool lower = ((lane & jj) == 0);
                    const bool keepmin = (lower == asc);
                    v0 = keepmin ? fminf(v0, o0) : fmaxf(v0, o0);
                    v1 = keepmin ? fminf(v1, o1) : fmaxf(v1, o1);
                }
            }
        }
        const float T = __shfl(v1, 9);          // element 19 = lane 9, reg 1
        if (lane == 0) Tq[qq] = T + MARGIN;
    }
    __syncthreads();

    // ------- Candidate chunks: every chunk that could hold a top-20 ---------
#pragma unroll
    for (int i = 0; i < QPL; ++i) {
        const int q = qh * QPL + i;
        if (mn[i] <= Tq[q]) {
            const int e = atomicAdd(&cnt2[q], 1);
            if (e < MAXC) cand[q][e] = c;
        }
    }
    __syncthreads();

    // ------- PASS 2 (sparse): exact distances in candidate chunks only ------
    // Wave g owns queries {g, g+8}; lane (w,j) = (lane>>4, lane&15) maps to
    // point n = w*WIN + c*JPW + j  (the chunk's TRUE point set).
#pragma unroll
    for (int rep = 0; rep < 2; ++rep) {
        const int q = wv + rep * 8;             // wave-uniform
        const int qg2 = blockIdx.x * NQB + q;
        const float qx2 = verts[qg2 * 3 + 0];
        const float qy2 = verts[qg2 * 3 + 1];
        const float qz2 = verts[qg2 * 3 + 2];
        const float qn2 = norm3(qx2, qy2, qz2);
        const float T = Tq[q];
        const int nc = min(cnt2[q], MAXC);
        for (int e = 0; e < nc; ++e) {          // wave-uniform loop
            const int n = (lane >> 4) * WIN + cand[q][e] * JPW + (lane & 15);
            const float px = verts[n * 3 + 0];
            const float py = verts[n * 3 + 1];
            const float pz = verts[n * 3 + 2];
            const float pw = norm3(px, py, pz);
            const float d = dist_exact(px, py, pz, pw, qx2, qy2, qz2, qn2);
            if (d <= T) {                       // ~25 hits/query total
                const int slot = atomicAdd(&cnt[q], 1);
                if (slot < CAP) { hbd[q][slot] = d; hbi[q][slot] = n; }
            }
        }
    }
    __syncthreads();

    // ------- Final: exact stable top-20 via u64 bitonic ---------------------
#pragma unroll
    for (int r = 0; r < 2; ++r) {
        const int qq = wv * 2 + r;
        const int kc = min(cnt[qq], CAP);       // kc >= 20 guaranteed
        unsigned long long key = ~0ULL;
        if (lane < kc) {
            const float d = hbd[qq][lane];
            unsigned u = __float_as_uint(d);
            u ^= ((unsigned)((int)u >> 31)) | 0x80000000u;   // order-preserving map
            key = ((unsigned long long)u << 32) | (unsigned)hbi[qq][lane];
        }
#pragma unroll
        for (int k = 2; k <= 64; k <<= 1) {
#pragma unroll
            for (int j = k >> 1; j >= 1; j >>= 1) {
                const unsigned long long o = __shfl_xor(key, j);
                const bool asc = ((lane & k) == 0);
                const bool lower = ((lane & j) == 0);
                const bool keepmin = (lower == asc);
                const bool lt = key < o;
                key = (keepmin == lt) ? key : o;
            }
        }
        if (lane < KK)
            out[(blockIdx.x * NQB + qq) * KK + lane] =
                (int)(unsigned)(key & 0xffffffffULL);
    }
}

extern "C" void kernel_launch(void* const* d_in, const int* in_sizes, int n_in,
                              void* d_out, int out_size, void* d_ws, size_t ws_size,
                              hipStream_t stream) {
    // d_in[0] = feats (unused). d_in[1] = vertices [4,8192,3] f32; batch 0 only.
    const float* verts = (const float*)d_in[1];
    int* out = (int*)d_out;
    knn_kernel<<<dim3(NPTS / NQB), dim3(THREADS), 0, stream>>>(verts, out);
}

// Round 10
// 33.847 us; speedup vs baseline: 1.2827x; 1.0541x over previous
//
#include <hip/hip_runtime.h>
#include <math.h>

#define KK 20
#define NPTS 8192
#define NQB 16              // queries per block
#define QPL 4               // queries per lane
#define NCH 128             // chunks per query (64 pts each, strided across windows)
#define THREADS 512
#define WIN 2048            // points per staged LDS window
#define NWIN 4
#define JPW (WIN / NCH)     // 16 candidates per chunk per window
#define PPT (WIN / THREADS) // 4 points staged per thread
#define CAP 64              // hit buffer capacity per query
#define MAXC 64             // candidate-chunk list capacity per query
#define MARGIN 4e-3f        // >> 2*max|d_fast - d_exact| (fp32 fma vs split)

// Exact (non-contracted) IEEE ops matching the NumPy reference bit-for-bit.
// np.sum (pairwise, n<8) accumulates ascending: (x^2 + y^2) + z^2.
__device__ __forceinline__ float norm3(float x, float y, float z) {
    return __fadd_rn(__fadd_rn(__fmul_rn(x, x), __fmul_rn(y, y)), __fmul_rn(z, z));
}

// np.einsum (optimize=False) remainder falls through DESCENDING for count=3:
// ((z*z') + y*y') + x*x'.  dist = ((-2*dot) + n_src) + n_dst.
__device__ __forceinline__ float dist_exact(float px, float py, float pz, float pw,
                                            float qx, float qy, float qz, float qn) {
    const float dot = __fadd_rn(
        __fadd_rn(__fmul_rn(pz, qz), __fmul_rn(py, qy)), __fmul_rn(px, qx));
    return __fadd_rn(__fadd_rn(__fmul_rn(dot, -2.0f), pw), qn);
}

extern "C" __global__ __launch_bounds__(THREADS, 4)
void knn_kernel(const float* __restrict__ verts, int* __restrict__ out)
{
    // Static LDS ~58 KB -> 2 blocks/CU, grid 512 = exactly 2/CU.
    __shared__ float4 pts[WIN];                 // 32768 B
    __shared__ float  vdump[NCH][NQB + 1];      //  8704 B
    __shared__ float  hbd[NQB][CAP];            //  4096 B
    __shared__ int    hbi[NQB][CAP];            //  4096 B
    __shared__ int    cand[NQB][MAXC];          //  4096 B
    __shared__ float  Tq[NQB];
    __shared__ int    cnt[NQB];
    __shared__ int    cnt2[NQB];

    const int t    = threadIdx.x;
    const int lane = t & 63;
    const int wv   = t >> 6;          // wave 0..7
    const int c    = t >> 2;          // chunk 0..127
    const int qh   = t & 3;           // query group 0..3
    const int xr   = c & 15;          // read-order bank-spread XOR (R6-proven)
    const int qbase = blockIdx.x * NQB + qh * QPL;

    if (t < NQB) { cnt[t] = 0; cnt2[t] = 0; }

    // Register tile: 4 queries per lane. Fast path uses folded -2*q coords and
    // OMITS qn inside the min (constant shift per query, re-added once).
    float qx2[QPL], qy2[QPL], qz2[QPL], qn[QPL];
#pragma unroll
    for (int i = 0; i < QPL; ++i) {
        const float x = verts[(qbase + i) * 3 + 0];
        const float y = verts[(qbase + i) * 3 + 1];
        const float z = verts[(qbase + i) * 3 + 2];
        qn[i] = norm3(x, y, z);
        qx2[i] = -2.0f * x; qy2[i] = -2.0f * y; qz2[i] = -2.0f * z;
    }

    // Issue-early / commit-late staging (T14).
    float sx[PPT], sy[PPT], sz[PPT];
    auto issue = [&](int w) {
#pragma unroll
        for (int i = 0; i < PPT; ++i) {
            const int n = w * WIN + i * THREADS + t;
            sx[i] = verts[n * 3 + 0];
            sy[i] = verts[n * 3 + 1];
            sz[i] = verts[n * 3 + 2];
        }
    };
    auto commit = [&]() {
#pragma unroll
        for (int i = 0; i < PPT; ++i) {
            const int m = i * THREADS + t;
            pts[m] = make_float4(sx[i], sy[i], sz[i], norm3(sx[i], sy[i], sz[i]));
        }
    };

    // ---------------- PASS 1: per-(chunk,query) MIN (shifted fast dist) -----
    // Chunk c's point set: { w*WIN + c*JPW + j : w in [0,NWIN), j in [0,JPW) }.
    // Shifted fast dist: fma(px,qx2, fma(py,qy2, fma(pz,qz2, pw)))  (no qn).
    float mn[QPL];
#pragma unroll
    for (int i = 0; i < QPL; ++i) mn[i] = INFINITY;

    issue(0); commit(); __syncthreads();
#pragma unroll 1
    for (int w = 0; w < NWIN; ++w) {
        if (w + 1 < NWIN) issue(w + 1);
#pragma unroll 4
        for (int v = 0; v < JPW; ++v) {
            const float4 p = pts[c * JPW + (v ^ xr)];
#pragma unroll
            for (int i = 0; i < QPL; ++i) {
                const float d = __builtin_fmaf(p.x, qx2[i],
                                __builtin_fmaf(p.y, qy2[i],
                                __builtin_fmaf(p.z, qz2[i], p.w)));
                mn[i] = fminf(mn[i], d);
            }
        }
        __syncthreads();
        if (w + 1 < NWIN) { commit(); __syncthreads(); }
    }

    // Re-add qn so vdump holds true fast distances (comparable to exact + T).
#pragma unroll
    for (int i = 0; i < QPL; ++i) {
        mn[i] += qn[i];
        vdump[c][qh * QPL + i] = mn[i];
    }
    __syncthreads();

    // ------- T' = 20th smallest of 128 chunk-minima + margin ----------------
    // Wave wv handles queries {2wv, 2wv+1}: 128-elem bitonic, 2 regs/lane.
#pragma unroll
    for (int r = 0; r < 2; ++r) {
        const int qq = wv * 2 + r;
        float v0 = vdump[lane * 2 + 0][qq];
        float v1 = vdump[lane * 2 + 1][qq];
#pragma unroll
        for (int k = 2; k <= 128; k <<= 1) {
#pragma unroll
            for (int j = k >> 1; j >= 1; j >>= 1) {
                const bool asc = ((lane & (k >> 1)) == 0);
                if (j == 1) {
                    const float lo = fminf(v0, v1), hi = fmaxf(v0, v1);
                    v0 = asc ? lo : hi;
                    v1 = asc ? hi : lo;
                } else {
                    const int jj = j >> 1;
                    const float o0 = __shfl_xor(v0, jj);
                    const float o1 = __shfl_xor(v1, jj);
                    const bool lower = ((lane & jj) == 0);
                    const bool keepmin = (lower == asc);
                    v0 = keepmin ? fminf(v0, o0) : fmaxf(v0, o0);
                    v1 = keepmin ? fminf(v1, o1) : fmaxf(v1, o1);
                }
            }
        }
        const float T = __shfl(v1, 9);          // element 19 = lane 9, reg 1
        if (lane == 0) Tq[qq] = T + MARGIN;
    }
    __syncthreads();

    // ------- Candidate chunks: every chunk that could hold a top-20 ---------
#pragma unroll
    for (int i = 0; i < QPL; ++i) {
        const int q = qh * QPL + i;
        if (mn[i] <= Tq[q]) {
            const int e = atomicAdd(&cnt2[q], 1);
            if (e < MAXC) cand[q][e] = c;
        }
    }
    __syncthreads();

    // ------- PASS 2 (sparse): exact distances, 4-deep load pipeline ---------
    // Wave g owns queries {g, g+8}; lane (w,j) = (lane>>4, lane&15) maps to
    // point n = w*WIN + c*JPW + j  (the chunk's TRUE point set).
#pragma unroll
    for (int rep = 0; rep < 2; ++rep) {
        const int q = wv + rep * 8;             // wave-uniform
        const int qg2 = blockIdx.x * NQB + q;
        const float qxe = verts[qg2 * 3 + 0];
        const float qye = verts[qg2 * 3 + 1];
        const float qze = verts[qg2 * 3 + 2];
        const float qne = norm3(qxe, qye, qze);
        const float T = Tq[q];
        const int nc = min(cnt2[q], MAXC);
        for (int e0 = 0; e0 < nc; e0 += 4) {    // wave-uniform groups of 4
            float PX[4], PY[4], PZ[4]; int NN[4];
#pragma unroll
            for (int u = 0; u < 4; ++u) {       // 12 independent loads issue
                const int e = e0 + u;
                const int cc = cand[q][e < nc ? e : 0];
                const int n = (lane >> 4) * WIN + cc * JPW + (lane & 15);
                NN[u] = n;
                PX[u] = verts[n * 3 + 0];
                PY[u] = verts[n * 3 + 1];
                PZ[u] = verts[n * 3 + 2];
            }
#pragma unroll
            for (int u = 0; u < 4; ++u) {
                if (e0 + u < nc) {
                    const float pw = norm3(PX[u], PY[u], PZ[u]);
                    const float d = dist_exact(PX[u], PY[u], PZ[u], pw,
                                               qxe, qye, qze, qne);
                    if (d <= T) {               // ~25 hits/query total
                        const int slot = atomicAdd(&cnt[q], 1);
                        if (slot < CAP) { hbd[q][slot] = d; hbi[q][slot] = NN[u]; }
                    }
                }
            }
        }
    }
    __syncthreads();

    // ------- Final: exact stable top-20 via u64 bitonic ---------------------
#pragma unroll
    for (int r = 0; r < 2; ++r) {
        const int qq = wv * 2 + r;
        const int kc = min(cnt[qq], CAP);       // kc >= 20 guaranteed
        unsigned long long key = ~0ULL;
        if (lane < kc) {
            const float d = hbd[qq][lane];
            unsigned u = __float_as_uint(d);
            u ^= ((unsigned)((int)u >> 31)) | 0x80000000u;   // order-preserving map
            key = ((unsigned long long)u << 32) | (unsigned)hbi[qq][lane];
        }
#pragma unroll
        for (int k = 2; k <= 64; k <<= 1) {
#pragma unroll
            for (int j = k >> 1; j >= 1; j >>= 1) {
                const unsigned long long o = __shfl_xor(key, j);
                const bool asc = ((lane & k) == 0);
                const bool lower = ((lane & j) == 0);
                const bool keepmin = (lower == asc);
                const bool lt = key < o;
                key = (keepmin == lt) ? key : o;
            }
        }
        if (lane < KK)
            out[(blockIdx.x * NQB + qq) * KK + lane] =
                (int)(unsigned)(key & 0xffffffffULL);
    }
}

extern "C" void kernel_launch(void* const* d_in, const int* in_sizes, int n_in,
                              void* d_out, int out_size, void* d_ws, size_t ws_size,
                              hipStream_t stream) {
    // d_in[0] = feats (unused). d_in[1] = vertices [4,8192,3] f32; batch 0 only.
    const float* verts = (const float*)d_in[1];
    int* out = (int*)d_out;
    knn_kernel<<<dim3(NPTS / NQB), dim3(THREADS), 0, stream>>>(verts, out);
}